// Round 1
// baseline (296.653 us; speedup 1.0000x reference)
//
#include <hip/hip_runtime.h>
#include <hip/hip_bf16.h>

// PrimaryCaps fused 1x1 convs -> per-n GEMM: Out[544,1024] = W[544,512] * X_n[512,1024]
// R3 restructure: one block per (n, 64-col m-tile) computes ALL 544 (padded 576) output
// rows -> x is read from HBM exactly once, no cross-block X re-reads through L2/L3.
// W is pre-converted to bf16 (zero-padded to 576 rows) into d_ws by prep_w; the main
// kernel streams A-fragments directly from L2 (590 KB, L2-resident per XCD) -- no A LDS,
// no barriers for A. LDS holds only the X tile: [64 m][64 k] bf16, double-buffered,
// 16 KB total, XOR slot swizzle (slot ^= m&7) -> conflict-free b128 writes AND reads.
// 256 threads = 4 o-waves x (9 frags of 16 rows) x 64 cols; acc 9x4 f32x4 = 144 VGPR,
// 2 blocks/CU. 8 k-steps (BK=64), single barrier each, X prefetched 1 step ahead.

typedef __attribute__((ext_vector_type(8))) short short8;
typedef __attribute__((ext_vector_type(4))) float f32x4;

#define A_CH   512
#define HW     1024
#define N_B    64
#define O_POSE 512
#define O_ACT  32
#define O_TOT  544
#define O_PAD  576            // 4 waves * 9 frags * 16 rows
#define TM     64
#define BK     64
#define NIT    (A_CH / BK)    // 8
#define NOF    9              // o-frags per wave

__device__ __forceinline__ unsigned pk(float lo, float hi) {
    __hip_bfloat162 h = __float22bfloat162_rn(make_float2(lo, hi));
    return *reinterpret_cast<unsigned*>(&h);
}

// ---- pre-kernel: W fp32 (512 pose rows ++ 32 act rows) -> bf16 [576][512] in ws,
// rows 544..575 zeroed. Fully rewritten every launch (re-poison safe).
__global__ __launch_bounds__(256) void prep_w(const float* __restrict__ Wp,
                                              const float* __restrict__ Wa,
                                              unsigned short* __restrict__ Wb) {
    const int r = blockIdx.x;
    const int c = threadIdx.x * 2;
    float2 v = make_float2(0.f, 0.f);
    if (r < O_POSE)     v = *(const float2*)(Wp + (size_t)r * A_CH + c);
    else if (r < O_TOT) v = *(const float2*)(Wa + (size_t)(r - O_POSE) * A_CH + c);
    __hip_bfloat162 h = __float22bfloat162_rn(v);
    *(unsigned*)(Wb + (size_t)r * A_CH + c) = *reinterpret_cast<unsigned*>(&h);
}

__global__ __launch_bounds__(256, 2) void caps_gemm(
    const float* __restrict__ x,            // [64,512,32,32] fp32
    const unsigned short* __restrict__ Wb,  // [576,512] bf16 (padded)
    const float* __restrict__ bp,           // [512]
    const float* __restrict__ ba,           // [32]
    float* __restrict__ out)                // poses [64,512,1024] ++ act [64,32,1024]
{
    // X tile [m][k] bf16, row = 128 B = 8 slots of 16 B; slot ^= (m&7) spreads the
    // column-slice reads/writes uniformly over all 8 superbanks (conflict-free).
    __shared__ __align__(16) short lds[2][TM * BK];   // 2 x 8 KB

    const int tid = threadIdx.x;
    const int m0  = blockIdx.x * TM;
    const int n   = blockIdx.y;

    const float* xn = x + (size_t)n * A_CH * HW + m0;

    // ---- X staging map: m = tid&63 (one column), k = (tid>>6)*16 + j, j=0..15.
    // 16 dword loads, each wave-instr = 256 B contiguous (m 0..63 at one k).
    const int sm = tid & 63;
    const int sk = (tid >> 6) * 16;
    const float* sbase = xn + (size_t)sk * HW + sm;

    const int s0   = sk >> 3;                    // even slot 0,2,4,6
    const int wswz = sm & 7;
    const int wr0  = sm * BK + ((s0 ^ wswz) << 3);        // short indices
    const int wr1  = sm * BK + (((s0 + 1) ^ wswz) << 3);

    float xr[16];
    auto load_x = [&](int it) {
#pragma unroll
        for (int j = 0; j < 16; ++j)
            xr[j] = sbase[(size_t)(it * BK + j) * HW];
    };
    auto store_x = [&](int buf) {
        short8 v0, v1;
#pragma unroll
        for (int j = 0; j < 4; ++j) {
            ((unsigned*)&v0)[j] = pk(xr[2 * j],     xr[2 * j + 1]);
            ((unsigned*)&v1)[j] = pk(xr[8 + 2 * j], xr[9 + 2 * j]);
        }
        *(short8*)&lds[buf][wr0] = v0;
        *(short8*)&lds[buf][wr1] = v1;
    };

    // ---- wave decomposition: wave w owns rows [w*144, w*144+144) x all 64 cols
    const int lane = tid & 63;
    const int w    = tid >> 6;
    const int l16  = lane & 15;
    const int g    = lane >> 4;

    // A-frag source: lane reads Wb[w*144 + of*16 + l16][it*64 + ks*32 + g*8 .. +7]
    const unsigned short* wlane = Wb + (size_t)(w * 144 + l16) * A_CH + g * 8;

    int bidx[4];
#pragma unroll
    for (int fm = 0; fm < 4; ++fm) bidx[fm] = (fm * 16 + l16) * BK;
    const int bswz = l16 & 7;

    f32x4 acc[NOF][4] = {};   // [o-frag][m-frag], 144 VGPRs

    load_x(0);
    store_x(0);
    __syncthreads();

    for (int it = 0; it < NIT; ++it) {
        const int cur = it & 1;
        if (it + 1 < NIT) load_x(it + 1);          // HBM prefetch rides under compute
#pragma unroll
        for (int ks = 0; ks < 2; ++ks) {
            short8 bF[4];
#pragma unroll
            for (int fm = 0; fm < 4; ++fm)
                bF[fm] = *(const short8*)&lds[cur][bidx[fm] + (((ks * 4 + g) ^ bswz) << 3)];
#pragma unroll
            for (int of = 0; of < NOF; ++of) {
                short8 aF = *(const short8*)(wlane + (size_t)of * 16 * A_CH + it * BK + ks * 32);
#pragma unroll
                for (int fm = 0; fm < 4; ++fm)
                    acc[of][fm] = __builtin_amdgcn_mfma_f32_16x16x32_bf16(
                        aF, bF[fm], acc[of][fm], 0, 0, 0);
            }
        }
        if (it + 1 < NIT) store_x(cur ^ 1);
        __syncthreads();   // single barrier per k-step (dbuf makes it safe)
    }

    // ---- epilogue: C/D layout col = lane&15, row = (lane>>4)*4 + reg
    float* actOut = out + (size_t)N_B * O_POSE * HW;
    const size_t poseN = (size_t)n * O_POSE * HW;
    const size_t actN  = (size_t)n * O_ACT * HW;
    const int ob = w * 144;
#pragma unroll
    for (int of = 0; of < NOF; ++of) {
#pragma unroll
        for (int i = 0; i < 4; ++i) {
            const int R = ob + of * 16 + g * 4 + i;
            if (R >= O_TOT) continue;              // padded rows 544..575
            if (R < O_POSE) {
                const float bias = bp[R];
#pragma unroll
                for (int fm = 0; fm < 4; ++fm) {
                    const int cc = m0 + fm * 16 + l16;
                    __builtin_nontemporal_store(acc[of][fm][i] + bias,
                                                &out[poseN + (size_t)R * HW + cc]);
                }
            } else {
                const float bias = ba[R - O_POSE];
#pragma unroll
                for (int fm = 0; fm < 4; ++fm) {
                    const int cc = m0 + fm * 16 + l16;
                    const float v = acc[of][fm][i] + bias;
                    __builtin_nontemporal_store(1.0f / (1.0f + __expf(-v)),
                                                &actOut[actN + (size_t)(R - O_POSE) * HW + cc]);
                }
            }
        }
    }
}

extern "C" void kernel_launch(void* const* d_in, const int* in_sizes, int n_in,
                              void* d_out, int out_size, void* d_ws, size_t ws_size,
                              hipStream_t stream) {
    (void)in_sizes; (void)n_in; (void)out_size; (void)ws_size;
    const float* x  = (const float*)d_in[0];
    const float* Wp = (const float*)d_in[1];
    const float* bp = (const float*)d_in[2];
    const float* Wa = (const float*)d_in[3];
    const float* ba = (const float*)d_in[4];
    unsigned short* Wb = (unsigned short*)d_ws;   // needs 576*512*2 = 589,824 B

    prep_w<<<dim3(O_PAD), dim3(256), 0, stream>>>(Wp, Wa, Wb);
    caps_gemm<<<dim3(HW / TM, N_B), dim3(256), 0, stream>>>(x, Wb, bp, ba, (float*)d_out);
}